// Round 5
// baseline (1611.333 us; speedup 1.0000x reference)
//
#include <hip/hip_runtime.h>
#include <stdint.h>

#define NN_NODE 50000
#define NN_EDGE 800000

typedef _Float16 f16;
typedef _Float16 f16x2 __attribute__((ext_vector_type(2)));
typedef _Float16 f16x4 __attribute__((ext_vector_type(4)));
typedef _Float16 f16x8 __attribute__((ext_vector_type(8)));
typedef float f32x4 __attribute__((ext_vector_type(4)));

// ---- workspace layout ----
#define WT_MW0   0        // [256][32]  (K=10 padded to 32)
#define WT_MW1   8192     // [256][256]
#define WT_MW2   73728    // [128][256]
#define WT_AW0   106496   // [128][128]
#define WT_AW1   122880   // [128][128]
#define WT_VW0   139264   // [256][128]
#define WT_VW1   172032   // [128][256]
#define WT_UW0   204800   // [256][128]
#define WT_UW1   237568   // [256][256]
#define WT_TOTAL 303104

#define V_OFF      606208ull                  // f16 v[E][128]   (receiver-sorted)
#define WL_OFF     205406208ull               // float wlog[E]   (receiver-sorted)
#define CNT_OFF    208606208ull               // int cnt/cursor[N]
#define BASE_OFF   208806208ull               // int base[N]
#define AGGR_OFF   209006208ull               // float aggr[N][128]

// XOR-swizzled LDS addressing: rows of 256 f16 = 32 chunks of 8 f16 (16B).
__device__ __forceinline__ int swz(int row, int col) {
    return row * 256 + ((((col >> 3) ^ (row & 7))) << 3) + (col & 7);
}

// ---- wave-autonomous fused MLP layer ----
// Each WAVE owns 32 edges (2 m-tiles of 16) and a private 32x256 f16 LDS
// slice. NO __syncthreads anywhere: same-wave LDS ops are processed in
// order, and all af reads complete (by MFMA data dependence) before the
// in-place epilogue writes. acc covers ALL N (128 VGPR max) with bias
// folded into the accumulator init, so K=256 layers stream K-halves with
// no output-defer and no hazards.
//
// R0-R4 lesson: the barrier-locked per-layer chain capped MfmaUtil at ~20%
// regardless of pipelining/occupancy tweaks; wave-autonomy removes the
// phase-lock entirely and lets desynced waves fill the matrix pipe.
//
// MFMA: A = weight W^T[n][k], B = activations; D: col=edge=lane&15,
// row=feature=quad*4+reg.
// EPI: 0 = relu -> LDS (in-place); 1 = logit (dot aw2, quad-reduce,
//      per-edge atomicAdd -> pos kept in register); 2 = relu -> global
//      v-store at slot pos (broadcast via shfl).
template<int K, int N, int EPI>
__device__ __forceinline__ void mlayerW(f16* sl, int inoff, int outoff,
        const f16* __restrict__ wt, const float* __restrict__ bias,
        const float* __restrict__ aw2, const float* __restrict__ ab2,
        float* __restrict__ wlog, int* __restrict__ cursor,
        const int* __restrict__ receivers, int e0w,
        f16* __restrict__ vout, int& pos, int lane)
{
    const int l15  = lane & 15;
    const int quad = lane >> 4;
    constexpr int NKS = K >> 5;                 // 1,4,8
    constexpr int NKH = (NKS > 4) ? 4 : NKS;    // k-slices per half
    constexpr int NH  = NKS / NKH;              // 1 or 2
    constexpr int NCT = N >> 4;                 // 8 or 16

    // accumulators for ALL N, bias-initialized (saves epilogue adds)
    f32x4 acc[NCT][2];
#pragma unroll
    for (int ct = 0; ct < NCT; ++ct) {
        const float4 bv = *(const float4*)(bias + ct * 16 + quad * 4);
        f32x4 a = {bv.x, bv.y, bv.z, bv.w};
        acc[ct][0] = a;
        acc[ct][1] = a;
    }

    f16x8 W[2][NKH];
    f16x8 af[2][NKH];

#pragma unroll
    for (int h = 0; h < NH; ++h) {
        // activation fragments for this K-half (own rows only)
#pragma unroll
        for (int m = 0; m < 2; ++m)
#pragma unroll
            for (int ks = 0; ks < NKH; ++ks)
                af[m][ks] = *(const f16x8*)(sl + swz(m * 16 + l15,
                                    inoff + (h * NKH + ks) * 32 + quad * 8));
#pragma unroll
        for (int m = 0; m < 2; ++m)
#pragma unroll
            for (int ks = 0; ks < NKH; ++ks)
                asm volatile("" : "+v"(af[m][ks]));   // pin: no re-read

        // weight double-buffer prologue: tiles ct=0,1
#pragma unroll
        for (int t = 0; t < 2; ++t) {
            const f16* wr = wt + (size_t)(t * 16 + l15) * K + h * NKH * 32 + quad * 8;
#pragma unroll
            for (int ks = 0; ks < NKH; ++ks) W[t][ks] = *(const f16x8*)(wr + ks * 32);
        }
#pragma unroll
        for (int ct = 0; ct < NCT; ++ct) {
#pragma unroll
            for (int m = 0; m < 2; ++m)
#pragma unroll
                for (int ks = 0; ks < NKH; ++ks)
                    acc[ct][m] = __builtin_amdgcn_mfma_f32_16x16x32_f16(
                        W[ct & 1][ks], af[m][ks], acc[ct][m], 0, 0, 0);
            if (ct + 2 < NCT) {   // recycle consumed slot
                const f16* wr = wt + (size_t)((ct + 2) * 16 + l15) * K + h * NKH * 32 + quad * 8;
#pragma unroll
                for (int ks = 0; ks < NKH; ++ks) W[ct & 1][ks] = *(const f16x8*)(wr + ks * 32);
            }
        }
    }

    // ---- epilogue ----
    if constexpr (EPI == 0) {
#pragma unroll
        for (int ct = 0; ct < NCT; ++ct) {
            const int f0 = ct * 16 + quad * 4;
#pragma unroll
            for (int m = 0; m < 2; ++m) {
                f16x4 o;
                o[0] = (f16)fmaxf(acc[ct][m][0], 0.f);
                o[1] = (f16)fmaxf(acc[ct][m][1], 0.f);
                o[2] = (f16)fmaxf(acc[ct][m][2], 0.f);
                o[3] = (f16)fmaxf(acc[ct][m][3], 0.f);
                *(f16x4*)(sl + swz(m * 16 + l15, outoff + f0)) = o;
            }
        }
    } else if constexpr (EPI == 1) {
        float p0 = 0.f, p1 = 0.f;
#pragma unroll
        for (int ct = 0; ct < NCT; ++ct) {
            const float4 awv = *(const float4*)(aw2 + ct * 16 + quad * 4);
            p0 += fmaxf(acc[ct][0][0], 0.f) * awv.x + fmaxf(acc[ct][0][1], 0.f) * awv.y
                + fmaxf(acc[ct][0][2], 0.f) * awv.z + fmaxf(acc[ct][0][3], 0.f) * awv.w;
            p1 += fmaxf(acc[ct][1][0], 0.f) * awv.x + fmaxf(acc[ct][1][1], 0.f) * awv.y
                + fmaxf(acc[ct][1][2], 0.f) * awv.z + fmaxf(acc[ct][1][3], 0.f) * awv.w;
        }
        p0 += __shfl_xor(p0, 16); p0 += __shfl_xor(p0, 32);
        p1 += __shfl_xor(p1, 16); p1 += __shfl_xor(p1, 32);
        // quad 0 handles edges 0-15 (m=0), quad 1 edges 16-31 (m=1)
        pos = 0;
        if (quad < 2) {
            float lg = (quad == 0 ? p0 : p1) + ab2[0];
            int ge = e0w + quad * 16 + l15;
            int r = receivers[ge];
            pos = atomicAdd(&cursor[r], 1);
            wlog[pos] = lg;
        }
    } else {   // EPI == 2: v direct to global at receiver-sorted slots
        const int s0 = __shfl(pos, l15);         // edge m=0 slot
        const int s1 = __shfl(pos, 16 + l15);    // edge m=1 slot
#pragma unroll
        for (int ct = 0; ct < NCT; ++ct) {
            const int f0 = ct * 16 + quad * 4;
            f16x4 o0, o1;
            o0[0] = (f16)fmaxf(acc[ct][0][0], 0.f);
            o0[1] = (f16)fmaxf(acc[ct][0][1], 0.f);
            o0[2] = (f16)fmaxf(acc[ct][0][2], 0.f);
            o0[3] = (f16)fmaxf(acc[ct][0][3], 0.f);
            o1[0] = (f16)fmaxf(acc[ct][1][0], 0.f);
            o1[1] = (f16)fmaxf(acc[ct][1][1], 0.f);
            o1[2] = (f16)fmaxf(acc[ct][1][2], 0.f);
            o1[3] = (f16)fmaxf(acc[ct][1][3], 0.f);
            *(f16x4*)(vout + (size_t)s0 * 128 + f0) = o0;
            *(f16x4*)(vout + (size_t)s1 * 128 + f0) = o1;
        }
    }
}

// ---- simple layer variant (node_kernel) ----
template<int K, int N>
__device__ __forceinline__ void mfma_layer_basic(const f16* in, int inoff,
        const f16* __restrict__ wt, const float* __restrict__ bias,
        f16* out, int outoff, int tid)
{
    const int wave = tid >> 6;
    const int lane = tid & 63;
    const int l15  = lane & 15;
    const int quad = lane >> 4;
    constexpr int NCT = N >> 4;
    constexpr int NKS = K >> 5;
    f16x8 af[4][NKS];
#pragma unroll
    for (int ms = 0; ms < 4; ++ms)
#pragma unroll
        for (int ks = 0; ks < NKS; ++ks)
            af[ms][ks] = *(const f16x8*)(in + swz(ms * 16 + l15, inoff + ks * 32 + quad * 8));
#pragma unroll 1
    for (int ct = wave; ct < NCT; ct += 4) {
        f16x8 bf[NKS];
        const f16* wrow = wt + (size_t)(ct * 16 + l15) * K + quad * 8;
#pragma unroll
        for (int ks = 0; ks < NKS; ++ks) bf[ks] = *(const f16x8*)(wrow + ks * 32);
        const int f0 = ct * 16 + quad * 4;
        const float4 bv = *(const float4*)(bias + f0);
#pragma unroll
        for (int ms = 0; ms < 4; ++ms) {
            f32x4 acc = {0.f, 0.f, 0.f, 0.f};
#pragma unroll
            for (int ks = 0; ks < NKS; ++ks)
                acc = __builtin_amdgcn_mfma_f32_16x16x32_f16(bf[ks], af[ms][ks], acc, 0, 0, 0);
            f16x4 o;
            o[0] = (f16)fmaxf(acc[0] + bv.x, 0.f);
            o[1] = (f16)fmaxf(acc[1] + bv.y, 0.f);
            o[2] = (f16)fmaxf(acc[2] + bv.z, 0.f);
            o[3] = (f16)fmaxf(acc[3] + bv.w, 0.f);
            *(f16x4*)(out + swz(ms * 16 + l15, outoff + f0)) = o;
        }
    }
}

// ---- prep: transpose-convert weights to f16 [N][Kpad] ----
struct WSeg { const float* src; int K, N, Kpad, dstOff; };
struct WSegs { WSeg s[9]; };

__global__ void prep_kernel(WSegs segs, f16* __restrict__ wt) {
    int idx = blockIdx.x * 256 + threadIdx.x;
    if (idx >= WT_TOTAL) return;
    int off = idx;
#pragma unroll
    for (int i = 0; i < 9; ++i) {
        int sz = segs.s[i].N * segs.s[i].Kpad;
        if (off < sz) {
            int n = off / segs.s[i].Kpad;
            int k = off - n * segs.s[i].Kpad;
            f16 val = (f16)0.f;
            if (k < segs.s[i].K) val = (f16)segs.s[i].src[k * segs.s[i].N + n];
            wt[segs.s[i].dstOff + off] = val;
            return;
        }
        off -= sz;
    }
}

// ---- sort step 1: histogram of receivers ----
__global__ void hist_kernel(const int* __restrict__ receivers, int* __restrict__ cnt) {
    int e = blockIdx.x * 256 + threadIdx.x;
    atomicAdd(&cnt[receivers[e]], 1);
}

// ---- sort step 2: exclusive scan ----
__global__ __launch_bounds__(1024) void scan_kernel(int* __restrict__ cnt, int* __restrict__ base) {
    __shared__ int psum[1024];
    const int tid = threadIdx.x;
    const int CH = (NN_NODE + 1023) / 1024;
    const int lo = tid * CH;
    const int hi = min(lo + CH, NN_NODE);
    int s = 0;
    for (int i = lo; i < hi; ++i) s += cnt[i];
    psum[tid] = s;
    __syncthreads();
    for (int d = 1; d < 1024; d <<= 1) {
        int v = (tid >= d) ? psum[tid - d] : 0;
        __syncthreads();
        psum[tid] += v;
        __syncthreads();
    }
    int run = psum[tid] - s;
    for (int i = lo; i < hi; ++i) {
        int c = cnt[i];
        base[i] = run;
        cnt[i] = run;
        run += c;
    }
}

// ---- K1: per-edge encoder + attention logit + value ----
// 128-thread blocks = 2 INDEPENDENT waves, 32 edges each, 16KB LDS slice
// each. Zero __syncthreads. Waves of a block run identical code ~in phase,
// so the trailing wave's weight loads hit L1.
__global__ __launch_bounds__(128, 2) void edge_kernel(
        const float* __restrict__ nodes, const float* __restrict__ edges,
        const int* __restrict__ senders, const int* __restrict__ receivers,
        const f16* __restrict__ wt,
        const float* __restrict__ mb0, const float* __restrict__ mb1, const float* __restrict__ mb2,
        const float* __restrict__ ab0, const float* __restrict__ ab1,
        const float* __restrict__ aw2, const float* __restrict__ ab2,
        const float* __restrict__ vb0, const float* __restrict__ vb1,
        f16* __restrict__ vout, float* __restrict__ wlog, int* __restrict__ cursor)
{
    __shared__ f16 buf[2 * 32 * 256];   // 32 KB total, 16 KB per wave
    const int tid  = threadIdx.x;
    const int wave = tid >> 6;
    const int lane = tid & 63;
    f16* sl = buf + wave * 32 * 256;
    const int e0w = blockIdx.x * 64 + wave * 32;

    // stage z into own slice: 32 rows x 32 cols (K=10 padded to 32).
    // lane&31 = row; lane>>5 = g: g=0 writes chunks 0,1 (data), g=1 chunks 2,3 (zero).
    {
        const int er = lane & 31;
        const int g  = lane >> 5;
        f16x8 c0 = {(f16)0.f,(f16)0.f,(f16)0.f,(f16)0.f,(f16)0.f,(f16)0.f,(f16)0.f,(f16)0.f};
        f16x8 c1 = c0;
        if (g == 0) {
            int ge = e0w + er;
            int s = senders[ge];
            int r = receivers[ge];
            const float2 ev0 = *(const float2*)(edges + (size_t)ge * 4);
            const float2 ev1 = *(const float2*)(edges + (size_t)ge * 4 + 2);
            c0[0] = (f16)nodes[s * 3 + 0]; c0[1] = (f16)nodes[s * 3 + 1]; c0[2] = (f16)nodes[s * 3 + 2];
            c0[3] = (f16)nodes[r * 3 + 0]; c0[4] = (f16)nodes[r * 3 + 1]; c0[5] = (f16)nodes[r * 3 + 2];
            c0[6] = (f16)ev0.x; c0[7] = (f16)ev0.y;
            c1[0] = (f16)ev1.x; c1[1] = (f16)ev1.y;
        }
        *(f16x8*)(sl + er * 256 + (((2 * g + 0) ^ (er & 7)) << 3)) = c0;
        *(f16x8*)(sl + er * 256 + (((2 * g + 1) ^ (er & 7)) << 3)) = c1;
    }
    asm volatile("" ::: "memory");   // keep LDS program order (no HW cost)

    int pos = 0;
    // L1: z(0-31) -> a1(0-255)
    mlayerW< 32, 256, 0>(sl, 0, 0, wt + WT_MW0, mb0, nullptr, nullptr,
                         nullptr, nullptr, nullptr, 0, nullptr, pos, lane);
    asm volatile("" ::: "memory");
    // MW1: a1 -> a2 (0-255), in-place
    mlayerW<256, 256, 0>(sl, 0, 0, wt + WT_MW1, mb1, nullptr, nullptr,
                         nullptr, nullptr, nullptr, 0, nullptr, pos, lane);
    asm volatile("" ::: "memory");
    // MW2: a2 -> q (0-127), in-place
    mlayerW<256, 128, 0>(sl, 0, 0, wt + WT_MW2, mb2, nullptr, nullptr,
                         nullptr, nullptr, nullptr, 0, nullptr, pos, lane);
    asm volatile("" ::: "memory");
    // AW0: q(0-127) -> h0(128-255)
    mlayerW<128, 128, 0>(sl, 0, 128, wt + WT_AW0, ab0, nullptr, nullptr,
                         nullptr, nullptr, nullptr, 0, nullptr, pos, lane);
    asm volatile("" ::: "memory");
    // AW1: h0 -> logits (atomic slot per edge; pos kept in register)
    mlayerW<128, 128, 1>(sl, 128, 0, wt + WT_AW1, ab1, aw2, ab2,
                         wlog, cursor, receivers, e0w, nullptr, pos, lane);
    asm volatile("" ::: "memory");
    // VW0: q(0-127) -> v1(0-255)
    mlayerW<128, 256, 0>(sl, 0, 0, wt + WT_VW0, vb0, nullptr, nullptr,
                         nullptr, nullptr, nullptr, 0, nullptr, pos, lane);
    asm volatile("" ::: "memory");
    // VW1: v1 -> v (global, receiver-sorted slots)
    mlayerW<256, 128, 2>(sl, 0, 0, wt + WT_VW1, vb1, nullptr, nullptr,
                         nullptr, nullptr, nullptr, 0, vout, pos, lane);
}

// ---- K2: per-node segmented softmax + weighted aggregation (1 wave / node) ----
__global__ __launch_bounds__(256) void aggregate_kernel(
        const float* __restrict__ wlog, const f16* __restrict__ v,
        const int* __restrict__ base, float* __restrict__ aggr)
{
    const int tid = threadIdx.x;
    const int n = blockIdx.x * 4 + (tid >> 6);
    const int lane = tid & 63;
    const int st = base[n];
    const int en = (n == NN_NODE - 1) ? NN_EDGE : base[n + 1];

    float mx = -1e9f;
    for (int i = st + lane; i < en; i += 64) mx = fmaxf(mx, wlog[i]);
#pragma unroll
    for (int d = 1; d < 64; d <<= 1) mx = fmaxf(mx, __shfl_xor(mx, d));

    float sm = 0.f;
    for (int i = st + lane; i < en; i += 64) sm += __expf(wlog[i] - mx);
#pragma unroll
    for (int d = 1; d < 64; d <<= 1) sm += __shfl_xor(sm, d);
    const float inv = 1.f / (sm + 1e-12f);

    float acc0 = 0.f, acc1 = 0.f;
    const f16* vp = v + (size_t)st * 128 + lane * 2;
    for (int i = st; i < en; ++i, vp += 128) {
        float attn = __expf(wlog[i] - mx) * inv;
        f16x2 vv = *(const f16x2*)vp;
        acc0 += attn * (float)vv[0];
        acc1 += attn * (float)vv[1];
    }
    float2 o; o.x = acc0; o.y = acc1;
    *(float2*)(aggr + (size_t)n * 128 + lane * 2) = o;
}

// ---- K3: node decoder (64-node tiles) ----
__global__ __launch_bounds__(256, 2) void node_kernel(
        const float* __restrict__ aggr, const f16* __restrict__ wt,
        const float* __restrict__ ub0, const float* __restrict__ ub1,
        const float* __restrict__ uw2, const float* __restrict__ ub2,
        float* __restrict__ out)
{
    __shared__ f16 ldsbuf[2 * 64 * 256];
    f16* bufA = ldsbuf;
    f16* bufB = ldsbuf + 64 * 256;
    const int tid = threadIdx.x;
    const int n0 = blockIdx.x * 64;
    {
        int row = tid >> 2, j = tid & 3;
        int n = n0 + row;
        if (n < NN_NODE) {
            const float4* src = (const float4*)(aggr + (size_t)n * 128 + j * 32);
#pragma unroll
            for (int i = 0; i < 8; ++i) {
                float4 t4 = src[i];
                int c = j * 32 + i * 4;
                bufA[swz(row, c + 0)] = (f16)t4.x;
                bufA[swz(row, c + 1)] = (f16)t4.y;
                bufA[swz(row, c + 2)] = (f16)t4.z;
                bufA[swz(row, c + 3)] = (f16)t4.w;
            }
        } else {
#pragma unroll
            for (int i = 0; i < 32; ++i) bufA[swz(row, j * 32 + i)] = (f16)0.f;
        }
    }
    __syncthreads();
    mfma_layer_basic<128, 256>(bufA, 0, wt + WT_UW0, ub0, bufB, 0, tid); __syncthreads();
    mfma_layer_basic<256, 256>(bufB, 0, wt + WT_UW1, ub1, bufA, 0, tid); __syncthreads();
    {
        int e = tid >> 2, part = tid & 3;
        float sum = 0.f;
        for (int c = part * 64; c < part * 64 + 64; ++c)
            sum += (float)bufA[swz(e, c)] * uw2[c];
        sum += __shfl_down(sum, 2);
        sum += __shfl_down(sum, 1);
        int n = n0 + e;
        if (part == 0 && n < NN_NODE) out[n] = sum + ub2[0];
    }
}

extern "C" void kernel_launch(void* const* d_in, const int* in_sizes, int n_in,
                              void* d_out, int out_size, void* d_ws, size_t ws_size,
                              hipStream_t stream)
{
    const float* nodes     = (const float*)d_in[0];
    const float* edges     = (const float*)d_in[1];
    const int*   senders   = (const int*)d_in[2];
    const int*   receivers = (const int*)d_in[3];
    const float* mw0 = (const float*)d_in[4];  const float* mb0 = (const float*)d_in[5];
    const float* mw1 = (const float*)d_in[6];  const float* mb1 = (const float*)d_in[7];
    const float* mw2 = (const float*)d_in[8];  const float* mb2 = (const float*)d_in[9];
    const float* aw0 = (const float*)d_in[10]; const float* ab0 = (const float*)d_in[11];
    const float* aw1 = (const float*)d_in[12]; const float* ab1 = (const float*)d_in[13];
    const float* aw2 = (const float*)d_in[14]; const float* ab2 = (const float*)d_in[15];
    const float* vw0 = (const float*)d_in[16]; const float* vb0 = (const float*)d_in[17];
    const float* vw1 = (const float*)d_in[18]; const float* vb1 = (const float*)d_in[19];
    const float* uw0 = (const float*)d_in[20]; const float* ub0 = (const float*)d_in[21];
    const float* uw1 = (const float*)d_in[22]; const float* ub1 = (const float*)d_in[23];
    const float* uw2 = (const float*)d_in[24]; const float* ub2 = (const float*)d_in[25];

    char* ws = (char*)d_ws;
    f16*   wt   = (f16*)ws;
    f16*   vbuf = (f16*)(ws + V_OFF);
    float* wlog = (float*)(ws + WL_OFF);
    int*   cnt  = (int*)(ws + CNT_OFF);
    int*   base = (int*)(ws + BASE_OFF);
    float* aggr = (float*)(ws + AGGR_OFF);
    float* out  = (float*)d_out;

    hipMemsetAsync(cnt, 0, NN_NODE * sizeof(int), stream);

    WSegs segs = {{
        { mw0,  10, 256,  32, WT_MW0 },
        { mw1, 256, 256, 256, WT_MW1 },
        { mw2, 256, 128, 256, WT_MW2 },
        { aw0, 128, 128, 128, WT_AW0 },
        { aw1, 128, 128, 128, WT_AW1 },
        { vw0, 128, 256, 128, WT_VW0 },
        { vw1, 256, 128, 256, WT_VW1 },
        { uw0, 128, 256, 128, WT_UW0 },
        { uw1, 256, 256, 256, WT_UW1 },
    }};
    prep_kernel<<<(WT_TOTAL + 255) / 256, 256, 0, stream>>>(segs, wt);

    hist_kernel<<<NN_EDGE / 256, 256, 0, stream>>>(receivers, cnt);
    scan_kernel<<<1, 1024, 0, stream>>>(cnt, base);

    edge_kernel<<<NN_EDGE / 64, 128, 0, stream>>>(nodes, edges, senders, receivers, wt,
        mb0, mb1, mb2, ab0, ab1, aw2, ab2, vb0, vb1, vbuf, wlog, cnt);

    aggregate_kernel<<<NN_NODE / 4, 256, 0, stream>>>(wlog, vbuf, base, aggr);

    node_kernel<<<(NN_NODE + 63) / 64, 256, 0, stream>>>(aggr, wt, ub0, ub1, uw2, ub2, out);
}

// Round 6
// 1510.709 us; speedup vs baseline: 1.0666x; 1.0666x over previous
//
#include <hip/hip_runtime.h>
#include <stdint.h>

#define NN_NODE 50000
#define NN_EDGE 800000

typedef _Float16 f16;
typedef _Float16 f16x2 __attribute__((ext_vector_type(2)));
typedef _Float16 f16x4 __attribute__((ext_vector_type(4)));
typedef _Float16 f16x8 __attribute__((ext_vector_type(8)));
typedef float f32x4 __attribute__((ext_vector_type(4)));

// ---- workspace layout ----
#define WT_MW0   0        // [256][32]  (K=10 padded to 32)
#define WT_MW1   8192     // [256][256]
#define WT_MW2   73728    // [128][256]
#define WT_AW0   106496   // [128][128]
#define WT_AW1   122880   // [128][128]
#define WT_VW0   139264   // [256][128]
#define WT_VW1   172032   // [128][256]
#define WT_UW0   204800   // [256][128]
#define WT_UW1   237568   // [256][256]
#define WT_TOTAL 303104

#define V_OFF      606208ull                  // f16 v[E][128]   (receiver-sorted)
#define WL_OFF     205406208ull               // float wlog[E]   (receiver-sorted)
#define CNT_OFF    208606208ull               // int cnt/cursor[N]
#define BASE_OFF   208806208ull               // int base[N]
#define AGGR_OFF   209006208ull               // float aggr[N][128]

// XOR-swizzled LDS addressing: rows of 256 f16 = 32 chunks of 8 f16 (16B).
__device__ __forceinline__ int swz(int row, int col) {
    return row * 256 + ((((col >> 3) ^ (row & 7))) << 3) + (col & 7);
}

// ---- wave-autonomous fused MLP layer (R6: full-K af + per-N-pass acc) ----
// One WAVE owns 32 edges (2 m-tiles) and a private 32x256 f16 LDS slice.
// Blocks are 64 threads = 1 wave -> barriers are structurally impossible;
// ~9 self-desynced waves/CU overlap MFMA / L2-weight / LDS / VALU phases
// (R1-R4: phase-locked blocks ran the pipes SERIALLY -> MfmaUtil pinned 20%).
//
// Register discipline (R2/R5 lesson: spills are fatal):
//   af FULL-K  : 2m x NKS f16x8  <= 64 VGPR, loaded ONCE, pinned.
//   acc per N-pass of 64 feats: 4ct x 2m f32x4 = 32 VGPR (bias folded in).
//   W double-buffer per K-half: 2 x NKH f16x8 = 32 VGPR.
//   peak ~150 << 256 cap (launch_bounds(64,2)).
// In-place safety: ALL af reads are issued (and pinned) before any epilogue
// write; same-wave LDS ops execute in order -> no WAR hazard, no barrier.
//
// MFMA: A = weight W^T[n][k], B = activations; D: col=edge=lane&15,
// row=feature=quad*4+reg.
// EPI: 0 = relu -> LDS (in-place); 1 = logit (dot aw2, quad-reduce,
//      per-edge atomicAdd -> pos kept in register); 2 = relu -> global
//      v-store at slot pos (broadcast via shfl).
template<int K, int N, int EPI>
__device__ __forceinline__ void mlayerA(f16* sl, int inoff, int outoff,
        const f16* __restrict__ wt, const float* __restrict__ bias,
        const float* __restrict__ aw2, const float* __restrict__ ab2,
        float* __restrict__ wlog, int* __restrict__ cursor,
        const int* __restrict__ receivers, int e0w,
        f16* __restrict__ vout, int& pos, int lane)
{
    const int l15  = lane & 15;
    const int quad = lane >> 4;
    constexpr int NKS = K >> 5;                 // 1,4,8
    constexpr int NKH = (NKS > 4) ? 4 : NKS;    // k-slices per half
    constexpr int NH  = NKS / NKH;              // 1 or 2
    constexpr int NCT = N >> 4;                 // 8 or 16
    constexpr int NP  = NCT / 4;                // N-passes of 64 feats (2 or 4)

    // full-K activation fragments: read ONCE, pinned -> in-place safe
    f16x8 af[2][NKS];
#pragma unroll
    for (int m = 0; m < 2; ++m)
#pragma unroll
        for (int ks = 0; ks < NKS; ++ks)
            af[m][ks] = *(const f16x8*)(sl + swz(m * 16 + l15, inoff + ks * 32 + quad * 8));
#pragma unroll
    for (int m = 0; m < 2; ++m)
#pragma unroll
        for (int ks = 0; ks < NKS; ++ks)
            asm volatile("" : "+v"(af[m][ks]));

    float preg[2];
    if constexpr (EPI == 1) { preg[0] = 0.f; preg[1] = 0.f; }
    int s0 = 0, s1 = 0;
    if constexpr (EPI == 2) {
        s0 = __shfl(pos, l15);          // slot of edge m=0 (set by quad0 lanes)
        s1 = __shfl(pos, 16 + l15);     // slot of edge m=1 (set by quad1 lanes)
    }

#pragma unroll
    for (int np = 0; np < NP; ++np) {
        f32x4 acc[4][2];
#pragma unroll
        for (int c = 0; c < 4; ++c) {
            const float4 bv = *(const float4*)(bias + (np * 4 + c) * 16 + quad * 4);
            f32x4 a = {bv.x, bv.y, bv.z, bv.w};
            acc[c][0] = a;
            acc[c][1] = a;
        }
#pragma unroll
        for (int h = 0; h < NH; ++h) {
            f16x8 W[2][NKH];
#pragma unroll
            for (int t = 0; t < 2; ++t) {
                const f16* wr = wt + (size_t)((np * 4 + t) * 16 + l15) * K + h * NKH * 32 + quad * 8;
#pragma unroll
                for (int ks = 0; ks < NKH; ++ks) W[t][ks] = *(const f16x8*)(wr + ks * 32);
            }
#pragma unroll
            for (int c = 0; c < 4; ++c) {
#pragma unroll
                for (int m = 0; m < 2; ++m)
#pragma unroll
                    for (int ks = 0; ks < NKH; ++ks)
                        acc[c][m] = __builtin_amdgcn_mfma_f32_16x16x32_f16(
                            W[c & 1][ks], af[m][h * NKH + ks], acc[c][m], 0, 0, 0);
                if (c < 2) {   // recycle consumed W slot with tile c+2
                    const f16* wr = wt + (size_t)((np * 4 + c + 2) * 16 + l15) * K + h * NKH * 32 + quad * 8;
#pragma unroll
                    for (int ks = 0; ks < NKH; ++ks) W[c & 1][ks] = *(const f16x8*)(wr + ks * 32);
                }
            }
        }

        // ---- epilogue for this N-pass ----
        if constexpr (EPI == 0) {
#pragma unroll
            for (int c = 0; c < 4; ++c) {
                const int f0 = (np * 4 + c) * 16 + quad * 4;
#pragma unroll
                for (int m = 0; m < 2; ++m) {
                    f16x4 o;
                    o[0] = (f16)fmaxf(acc[c][m][0], 0.f);
                    o[1] = (f16)fmaxf(acc[c][m][1], 0.f);
                    o[2] = (f16)fmaxf(acc[c][m][2], 0.f);
                    o[3] = (f16)fmaxf(acc[c][m][3], 0.f);
                    *(f16x4*)(sl + swz(m * 16 + l15, outoff + f0)) = o;
                }
            }
        } else if constexpr (EPI == 1) {
#pragma unroll
            for (int c = 0; c < 4; ++c) {
                const float4 awv = *(const float4*)(aw2 + (np * 4 + c) * 16 + quad * 4);
#pragma unroll
                for (int m = 0; m < 2; ++m)
                    preg[m] += fmaxf(acc[c][m][0], 0.f) * awv.x
                             + fmaxf(acc[c][m][1], 0.f) * awv.y
                             + fmaxf(acc[c][m][2], 0.f) * awv.z
                             + fmaxf(acc[c][m][3], 0.f) * awv.w;
            }
        } else {   // EPI == 2: v direct to global at receiver-sorted slots
#pragma unroll
            for (int c = 0; c < 4; ++c) {
                const int f0 = (np * 4 + c) * 16 + quad * 4;
                f16x4 o0, o1;
                o0[0] = (f16)fmaxf(acc[c][0][0], 0.f);
                o0[1] = (f16)fmaxf(acc[c][0][1], 0.f);
                o0[2] = (f16)fmaxf(acc[c][0][2], 0.f);
                o0[3] = (f16)fmaxf(acc[c][0][3], 0.f);
                o1[0] = (f16)fmaxf(acc[c][1][0], 0.f);
                o1[1] = (f16)fmaxf(acc[c][1][1], 0.f);
                o1[2] = (f16)fmaxf(acc[c][1][2], 0.f);
                o1[3] = (f16)fmaxf(acc[c][1][3], 0.f);
                *(f16x4*)(vout + (size_t)s0 * 128 + f0) = o0;
                *(f16x4*)(vout + (size_t)s1 * 128 + f0) = o1;
            }
        }
    }

    if constexpr (EPI == 1) {
        preg[0] += __shfl_xor(preg[0], 16); preg[0] += __shfl_xor(preg[0], 32);
        preg[1] += __shfl_xor(preg[1], 16); preg[1] += __shfl_xor(preg[1], 32);
        pos = 0;
        // quad 0 handles edges 0-15 (m=0), quad 1 edges 16-31 (m=1)
        if (quad < 2) {
            float lg = (quad == 0 ? preg[0] : preg[1]) + ab2[0];
            int ge = e0w + quad * 16 + l15;
            int r = receivers[ge];
            pos = atomicAdd(&cursor[r], 1);
            wlog[pos] = lg;
        }
    }
}

// ---- simple layer variant (node_kernel) ----
template<int K, int N>
__device__ __forceinline__ void mfma_layer_basic(const f16* in, int inoff,
        const f16* __restrict__ wt, const float* __restrict__ bias,
        f16* out, int outoff, int tid)
{
    const int wave = tid >> 6;
    const int lane = tid & 63;
    const int l15  = lane & 15;
    const int quad = lane >> 4;
    constexpr int NCT = N >> 4;
    constexpr int NKS = K >> 5;
    f16x8 af[4][NKS];
#pragma unroll
    for (int ms = 0; ms < 4; ++ms)
#pragma unroll
        for (int ks = 0; ks < NKS; ++ks)
            af[ms][ks] = *(const f16x8*)(in + swz(ms * 16 + l15, inoff + ks * 32 + quad * 8));
#pragma unroll 1
    for (int ct = wave; ct < NCT; ct += 4) {
        f16x8 bf[NKS];
        const f16* wrow = wt + (size_t)(ct * 16 + l15) * K + quad * 8;
#pragma unroll
        for (int ks = 0; ks < NKS; ++ks) bf[ks] = *(const f16x8*)(wrow + ks * 32);
        const int f0 = ct * 16 + quad * 4;
        const float4 bv = *(const float4*)(bias + f0);
#pragma unroll
        for (int ms = 0; ms < 4; ++ms) {
            f32x4 acc = {0.f, 0.f, 0.f, 0.f};
#pragma unroll
            for (int ks = 0; ks < NKS; ++ks)
                acc = __builtin_amdgcn_mfma_f32_16x16x32_f16(bf[ks], af[ms][ks], acc, 0, 0, 0);
            f16x4 o;
            o[0] = (f16)fmaxf(acc[0] + bv.x, 0.f);
            o[1] = (f16)fmaxf(acc[1] + bv.y, 0.f);
            o[2] = (f16)fmaxf(acc[2] + bv.z, 0.f);
            o[3] = (f16)fmaxf(acc[3] + bv.w, 0.f);
            *(f16x4*)(out + swz(ms * 16 + l15, outoff + f0)) = o;
        }
    }
}

// ---- prep: transpose-convert weights to f16 [N][Kpad] ----
struct WSeg { const float* src; int K, N, Kpad, dstOff; };
struct WSegs { WSeg s[9]; };

__global__ void prep_kernel(WSegs segs, f16* __restrict__ wt) {
    int idx = blockIdx.x * 256 + threadIdx.x;
    if (idx >= WT_TOTAL) return;
    int off = idx;
#pragma unroll
    for (int i = 0; i < 9; ++i) {
        int sz = segs.s[i].N * segs.s[i].Kpad;
        if (off < sz) {
            int n = off / segs.s[i].Kpad;
            int k = off - n * segs.s[i].Kpad;
            f16 val = (f16)0.f;
            if (k < segs.s[i].K) val = (f16)segs.s[i].src[k * segs.s[i].N + n];
            wt[segs.s[i].dstOff + off] = val;
            return;
        }
        off -= sz;
    }
}

// ---- sort step 1: histogram of receivers ----
__global__ void hist_kernel(const int* __restrict__ receivers, int* __restrict__ cnt) {
    int e = blockIdx.x * 256 + threadIdx.x;
    atomicAdd(&cnt[receivers[e]], 1);
}

// ---- sort step 2: exclusive scan ----
__global__ __launch_bounds__(1024) void scan_kernel(int* __restrict__ cnt, int* __restrict__ base) {
    __shared__ int psum[1024];
    const int tid = threadIdx.x;
    const int CH = (NN_NODE + 1023) / 1024;
    const int lo = tid * CH;
    const int hi = min(lo + CH, NN_NODE);
    int s = 0;
    for (int i = lo; i < hi; ++i) s += cnt[i];
    psum[tid] = s;
    __syncthreads();
    for (int d = 1; d < 1024; d <<= 1) {
        int v = (tid >= d) ? psum[tid - d] : 0;
        __syncthreads();
        psum[tid] += v;
        __syncthreads();
    }
    int run = psum[tid] - s;
    for (int i = lo; i < hi; ++i) {
        int c = cnt[i];
        base[i] = run;
        cnt[i] = run;
        run += c;
    }
}

// ---- K1: per-edge encoder + attention logit + value ----
// 64-thread blocks = 1 autonomous wave, 32 edges, 16KB private LDS.
// Zero barriers; ~9 blocks/CU self-desync so MFMA/L2/LDS/VALU overlap.
__global__ __launch_bounds__(64, 2) void edge_kernel(
        const float* __restrict__ nodes, const float* __restrict__ edges,
        const int* __restrict__ senders, const int* __restrict__ receivers,
        const f16* __restrict__ wt,
        const float* __restrict__ mb0, const float* __restrict__ mb1, const float* __restrict__ mb2,
        const float* __restrict__ ab0, const float* __restrict__ ab1,
        const float* __restrict__ aw2, const float* __restrict__ ab2,
        const float* __restrict__ vb0, const float* __restrict__ vb1,
        f16* __restrict__ vout, float* __restrict__ wlog, int* __restrict__ cursor)
{
    __shared__ f16 sl[32 * 256];   // 16 KB, wave-private
    const int lane = threadIdx.x;
    const int e0w = blockIdx.x * 32;

    // stage z: 32 rows x 32 cols (K=10 padded to 32).
    // lane&31 = row; lane>>5 = g: g=0 writes chunks 0,1 (data), g=1 chunks 2,3 (zero).
    {
        const int er = lane & 31;
        const int g  = lane >> 5;
        f16x8 c0 = {(f16)0.f,(f16)0.f,(f16)0.f,(f16)0.f,(f16)0.f,(f16)0.f,(f16)0.f,(f16)0.f};
        f16x8 c1 = c0;
        if (g == 0) {
            int ge = e0w + er;
            int s = senders[ge];
            int r = receivers[ge];
            const float2 ev0 = *(const float2*)(edges + (size_t)ge * 4);
            const float2 ev1 = *(const float2*)(edges + (size_t)ge * 4 + 2);
            c0[0] = (f16)nodes[s * 3 + 0]; c0[1] = (f16)nodes[s * 3 + 1]; c0[2] = (f16)nodes[s * 3 + 2];
            c0[3] = (f16)nodes[r * 3 + 0]; c0[4] = (f16)nodes[r * 3 + 1]; c0[5] = (f16)nodes[r * 3 + 2];
            c0[6] = (f16)ev0.x; c0[7] = (f16)ev0.y;
            c1[0] = (f16)ev1.x; c1[1] = (f16)ev1.y;
        }
        *(f16x8*)(sl + er * 256 + (((2 * g + 0) ^ (er & 7)) << 3)) = c0;
        *(f16x8*)(sl + er * 256 + (((2 * g + 1) ^ (er & 7)) << 3)) = c1;
    }
    asm volatile("" ::: "memory");   // keep LDS program order

    int pos = 0;
    // L1: z(0-31) -> a1(0-255)
    mlayerA< 32, 256, 0>(sl, 0, 0, wt + WT_MW0, mb0, nullptr, nullptr,
                         nullptr, nullptr, nullptr, 0, nullptr, pos, lane);
    asm volatile("" ::: "memory");
    // MW1: a1 -> a2 (0-255), in-place (af full-K read first)
    mlayerA<256, 256, 0>(sl, 0, 0, wt + WT_MW1, mb1, nullptr, nullptr,
                         nullptr, nullptr, nullptr, 0, nullptr, pos, lane);
    asm volatile("" ::: "memory");
    // MW2: a2 -> q (0-127), in-place
    mlayerA<256, 128, 0>(sl, 0, 0, wt + WT_MW2, mb2, nullptr, nullptr,
                         nullptr, nullptr, nullptr, 0, nullptr, pos, lane);
    asm volatile("" ::: "memory");
    // AW0: q(0-127) -> h0(128-255)
    mlayerA<128, 128, 0>(sl, 0, 128, wt + WT_AW0, ab0, nullptr, nullptr,
                         nullptr, nullptr, nullptr, 0, nullptr, pos, lane);
    asm volatile("" ::: "memory");
    // AW1: h0 -> logits (atomic slot per edge; pos kept in register)
    mlayerA<128, 128, 1>(sl, 128, 0, wt + WT_AW1, ab1, aw2, ab2,
                         wlog, cursor, receivers, e0w, nullptr, pos, lane);
    asm volatile("" ::: "memory");
    // VW0: q(0-127) -> v1(0-255), in-place (af full-K read first)
    mlayerA<128, 256, 0>(sl, 0, 0, wt + WT_VW0, vb0, nullptr, nullptr,
                         nullptr, nullptr, nullptr, 0, nullptr, pos, lane);
    asm volatile("" ::: "memory");
    // VW1: v1 -> v (global, receiver-sorted slots)
    mlayerA<256, 128, 2>(sl, 0, 0, wt + WT_VW1, vb1, nullptr, nullptr,
                         nullptr, nullptr, nullptr, 0, vout, pos, lane);
}

// ---- K2: per-node segmented softmax + weighted aggregation (1 wave / node) ----
__global__ __launch_bounds__(256) void aggregate_kernel(
        const float* __restrict__ wlog, const f16* __restrict__ v,
        const int* __restrict__ base, float* __restrict__ aggr)
{
    const int tid = threadIdx.x;
    const int n = blockIdx.x * 4 + (tid >> 6);
    const int lane = tid & 63;
    const int st = base[n];
    const int en = (n == NN_NODE - 1) ? NN_EDGE : base[n + 1];

    float mx = -1e9f;
    for (int i = st + lane; i < en; i += 64) mx = fmaxf(mx, wlog[i]);
#pragma unroll
    for (int d = 1; d < 64; d <<= 1) mx = fmaxf(mx, __shfl_xor(mx, d));

    float sm = 0.f;
    for (int i = st + lane; i < en; i += 64) sm += __expf(wlog[i] - mx);
#pragma unroll
    for (int d = 1; d < 64; d <<= 1) sm += __shfl_xor(sm, d);
    const float inv = 1.f / (sm + 1e-12f);

    float acc0 = 0.f, acc1 = 0.f;
    const f16* vp = v + (size_t)st * 128 + lane * 2;
    for (int i = st; i < en; ++i, vp += 128) {
        float attn = __expf(wlog[i] - mx) * inv;
        f16x2 vv = *(const f16x2*)vp;
        acc0 += attn * (float)vv[0];
        acc1 += attn * (float)vv[1];
    }
    float2 o; o.x = acc0; o.y = acc1;
    *(float2*)(aggr + (size_t)n * 128 + lane * 2) = o;
}

// ---- K3: node decoder (64-node tiles) ----
__global__ __launch_bounds__(256, 2) void node_kernel(
        const float* __restrict__ aggr, const f16* __restrict__ wt,
        const float* __restrict__ ub0, const float* __restrict__ ub1,
        const float* __restrict__ uw2, const float* __restrict__ ub2,
        float* __restrict__ out)
{
    __shared__ f16 ldsbuf[2 * 64 * 256];
    f16* bufA = ldsbuf;
    f16* bufB = ldsbuf + 64 * 256;
    const int tid = threadIdx.x;
    const int n0 = blockIdx.x * 64;
    {
        int row = tid >> 2, j = tid & 3;
        int n = n0 + row;
        if (n < NN_NODE) {
            const float4* src = (const float4*)(aggr + (size_t)n * 128 + j * 32);
#pragma unroll
            for (int i = 0; i < 8; ++i) {
                float4 t4 = src[i];
                int c = j * 32 + i * 4;
                bufA[swz(row, c + 0)] = (f16)t4.x;
                bufA[swz(row, c + 1)] = (f16)t4.y;
                bufA[swz(row, c + 2)] = (f16)t4.z;
                bufA[swz(row, c + 3)] = (f16)t4.w;
            }
        } else {
#pragma unroll
            for (int i = 0; i < 32; ++i) bufA[swz(row, j * 32 + i)] = (f16)0.f;
        }
    }
    __syncthreads();
    mfma_layer_basic<128, 256>(bufA, 0, wt + WT_UW0, ub0, bufB, 0, tid); __syncthreads();
    mfma_layer_basic<256, 256>(bufB, 0, wt + WT_UW1, ub1, bufA, 0, tid); __syncthreads();
    {
        int e = tid >> 2, part = tid & 3;
        float sum = 0.f;
        for (int c = part * 64; c < part * 64 + 64; ++c)
            sum += (float)bufA[swz(e, c)] * uw2[c];
        sum += __shfl_down(sum, 2);
        sum += __shfl_down(sum, 1);
        int n = n0 + e;
        if (part == 0 && n < NN_NODE) out[n] = sum + ub2[0];
    }
}

extern "C" void kernel_launch(void* const* d_in, const int* in_sizes, int n_in,
                              void* d_out, int out_size, void* d_ws, size_t ws_size,
                              hipStream_t stream)
{
    const float* nodes     = (const float*)d_in[0];
    const float* edges     = (const float*)d_in[1];
    const int*   senders   = (const int*)d_in[2];
    const int*   receivers = (const int*)d_in[3];
    const float* mw0 = (const float*)d_in[4];  const float* mb0 = (const float*)d_in[5];
    const float* mw1 = (const float*)d_in[6];  const float* mb1 = (const float*)d_in[7];
    const float* mw2 = (const float*)d_in[8];  const float* mb2 = (const float*)d_in[9];
    const float* aw0 = (const float*)d_in[10]; const float* ab0 = (const float*)d_in[11];
    const float* aw1 = (const float*)d_in[12]; const float* ab1 = (const float*)d_in[13];
    const float* aw2 = (const float*)d_in[14]; const float* ab2 = (const float*)d_in[15];
    const float* vw0 = (const float*)d_in[16]; const float* vb0 = (const float*)d_in[17];
    const float* vw1 = (const float*)d_in[18]; const float* vb1 = (const float*)d_in[19];
    const float* uw0 = (const float*)d_in[20]; const float* ub0 = (const float*)d_in[21];
    const float* uw1 = (const float*)d_in[22]; const float* ub1 = (const float*)d_in[23];
    const float* uw2 = (const float*)d_in[24]; const float* ub2 = (const float*)d_in[25];

    char* ws = (char*)d_ws;
    f16*   wt   = (f16*)ws;
    f16*   vbuf = (f16*)(ws + V_OFF);
    float* wlog = (float*)(ws + WL_OFF);
    int*   cnt  = (int*)(ws + CNT_OFF);
    int*   base = (int*)(ws + BASE_OFF);
    float* aggr = (float*)(ws + AGGR_OFF);
    float* out  = (float*)d_out;

    hipMemsetAsync(cnt, 0, NN_NODE * sizeof(int), stream);

    WSegs segs = {{
        { mw0,  10, 256,  32, WT_MW0 },
        { mw1, 256, 256, 256, WT_MW1 },
        { mw2, 256, 128, 256, WT_MW2 },
        { aw0, 128, 128, 128, WT_AW0 },
        { aw1, 128, 128, 128, WT_AW1 },
        { vw0, 128, 256, 128, WT_VW0 },
        { vw1, 256, 128, 256, WT_VW1 },
        { uw0, 128, 256, 128, WT_UW0 },
        { uw1, 256, 256, 256, WT_UW1 },
    }};
    prep_kernel<<<(WT_TOTAL + 255) / 256, 256, 0, stream>>>(segs, wt);

    hist_kernel<<<NN_EDGE / 256, 256, 0, stream>>>(receivers, cnt);
    scan_kernel<<<1, 1024, 0, stream>>>(cnt, base);

    edge_kernel<<<NN_EDGE / 32, 64, 0, stream>>>(nodes, edges, senders, receivers, wt,
        mb0, mb1, mb2, ab0, ab1, aw2, ab2, vb0, vb1, vbuf, wlog, cnt);

    aggregate_kernel<<<NN_NODE / 4, 256, 0, stream>>>(wlog, vbuf, base, aggr);

    node_kernel<<<(NN_NODE + 63) / 64, 256, 0, stream>>>(aggr, wt, ub0, ub1, uw2, ub2, out);
}

// Round 7
// 976.310 us; speedup vs baseline: 1.6504x; 1.5474x over previous
//
#include <hip/hip_runtime.h>
#include <stdint.h>

#define NN_NODE 50000
#define NN_EDGE 800000

typedef _Float16 f16;
typedef _Float16 f16x2 __attribute__((ext_vector_type(2)));
typedef _Float16 f16x4 __attribute__((ext_vector_type(4)));
typedef _Float16 f16x8 __attribute__((ext_vector_type(8)));
typedef float f32x4 __attribute__((ext_vector_type(4)));

// ---- workspace layout ----
#define WT_MW0   0        // [256][32]  (K=10 padded to 32)
#define WT_MW1   8192     // [256][256]
#define WT_MW2   73728    // [128][256]
#define WT_AW0   106496   // [128][128]
#define WT_AW1   122880   // [128][128]
#define WT_VW0   139264   // [256][128]
#define WT_VW1   172032   // [128][256]
#define WT_UW0   204800   // [256][128]
#define WT_UW1   237568   // [256][256]
#define WT_TOTAL 303104

#define V_OFF      606208ull                  // f16 v[E][128]   (receiver-sorted)
#define WL_OFF     205406208ull               // float wlog[E]   (receiver-sorted)
#define CNT_OFF    208606208ull               // int cnt/cursor[N]
#define BASE_OFF   208806208ull               // int base[N]
#define AGGR_OFF   209006208ull               // float aggr[N][128]

// XOR-swizzled LDS addressing: rows of 256 f16 = 32 chunks of 8 f16 (16B).
__device__ __forceinline__ int swz(int row, int col) {
    return row * 256 + ((((col >> 3) ^ (row & 7))) << 3) + (col & 7);
}

// ---- register-lean fused MLP layer (R7) ----
// Shape: 64 edges (4 m-tiles) x N feats; 4 waves, wave owns cts {wave+4i}.
// acc holds ALL owned ct-tiles (<=64 VGPR) so every af element is read from
// LDS exactly ONCE per layer (same LDS traffic as the 692us R1 kernel).
// af streams in K-chunks of 64 (32 VGPR, kc loop kept ROLLED to cap
// pressure); W is loaded per-ct with no double-buffer (8 VGPR).
// Peak live ~115-120 VGPR -> fits launch_bounds(256,4)'s 128 cap ->
// 4 blocks/CU = 16 waves/CU (R1-R4 had 8, phase-locked => MfmaUtil 20%).
// Intra-wave load stalls are covered by the 4 independently-phased blocks.
//
// In-place safety: all LDS reads happen in the kc loop; IBAR=1 inserts one
// __syncthreads() before the epilogue writes (cross-wave WAR fence).
// IBAR=0 when the write region is disjoint (AW0) or no LDS writes (AW1,VW1).
// EPI: 0 = relu -> LDS; 1 = logit partial (dot aw2 -> lpart, no LDS out);
//      2 = relu -> direct global v-store at spos slot.
template<int K, int N, int EPI, int IBAR>
__device__ __forceinline__ void mlayerR(f16* buf, int inoff, int outoff,
        const f16* __restrict__ wt, const float* __restrict__ bias,
        const float* __restrict__ aw2, float* lpart,
        f16* __restrict__ vout, const int* sposp, int tid)
{
    const int wave = tid >> 6;
    const int lane = tid & 63;
    const int l15  = lane & 15;
    const int quad = lane >> 4;
    constexpr int KS = (K >= 64) ? 2 : 1;     // k-slices per chunk
    constexpr int KC = KS * 32;               // chunk width (64 or 32)
    constexpr int NC = K / KC;                // chunks (1,2,4)
    constexpr int C  = (N >> 4) / 4;          // ct-tiles per wave (2 or 4)

    f32x4 acc[C][4];
#pragma unroll
    for (int ci = 0; ci < C; ++ci)
#pragma unroll
        for (int m = 0; m < 4; ++m)
            acc[ci][m] = (f32x4){0.f, 0.f, 0.f, 0.f};

#pragma unroll 1
    for (int kc = 0; kc < NC; ++kc) {
        // af chunk: 4 m-tiles x KS slices (32 VGPR at KS=2), read once, pinned
        f16x8 af[4][KS];
#pragma unroll
        for (int m = 0; m < 4; ++m)
#pragma unroll
            for (int ks = 0; ks < KS; ++ks)
                af[m][ks] = *(const f16x8*)(buf + swz(m * 16 + l15,
                                    inoff + kc * KC + ks * 32 + quad * 8));
#pragma unroll
        for (int m = 0; m < 4; ++m)
#pragma unroll
            for (int ks = 0; ks < KS; ++ks)
                asm volatile("" : "+v"(af[m][ks]));

#pragma unroll
        for (int ci = 0; ci < C; ++ci) {
            const int ct = wave + ci * 4;
            f16x8 W[KS];
            const f16* wr = wt + (size_t)(ct * 16 + l15) * K + kc * KC + quad * 8;
#pragma unroll
            for (int ks = 0; ks < KS; ++ks) W[ks] = *(const f16x8*)(wr + ks * 32);
#pragma unroll
            for (int m = 0; m < 4; ++m)
#pragma unroll
                for (int ks = 0; ks < KS; ++ks)
                    acc[ci][m] = __builtin_amdgcn_mfma_f32_16x16x32_f16(
                        W[ks], af[m][ks], acc[ci][m], 0, 0, 0);
        }
    }

    // cross-wave WAR fence for in-place update
    if constexpr (IBAR) __syncthreads();

    // ---- epilogue ----
    float preg[4];
    if constexpr (EPI == 1) {
#pragma unroll
        for (int m = 0; m < 4; ++m) preg[m] = 0.f;
    }
    int sposv[4];
    if constexpr (EPI == 2) {
#pragma unroll
        for (int m = 0; m < 4; ++m) sposv[m] = sposp[m * 16 + l15];
    }
#pragma unroll
    for (int ci = 0; ci < C; ++ci) {
        const int ct = wave + ci * 4;
        const int f0 = ct * 16 + quad * 4;
        const float4 bv = *(const float4*)(bias + f0);
        float4 awv;
        if constexpr (EPI == 1) awv = *(const float4*)(aw2 + f0);
#pragma unroll
        for (int m = 0; m < 4; ++m) {
            if constexpr (EPI == 0) {
                f16x4 o;
                o[0] = (f16)fmaxf(acc[ci][m][0] + bv.x, 0.f);
                o[1] = (f16)fmaxf(acc[ci][m][1] + bv.y, 0.f);
                o[2] = (f16)fmaxf(acc[ci][m][2] + bv.z, 0.f);
                o[3] = (f16)fmaxf(acc[ci][m][3] + bv.w, 0.f);
                *(f16x4*)(buf + swz(m * 16 + l15, outoff + f0)) = o;
            } else if constexpr (EPI == 1) {
                preg[m] += fmaxf(acc[ci][m][0] + bv.x, 0.f) * awv.x
                         + fmaxf(acc[ci][m][1] + bv.y, 0.f) * awv.y
                         + fmaxf(acc[ci][m][2] + bv.z, 0.f) * awv.z
                         + fmaxf(acc[ci][m][3] + bv.w, 0.f) * awv.w;
            } else {
                f16x4 o;
                o[0] = (f16)fmaxf(acc[ci][m][0] + bv.x, 0.f);
                o[1] = (f16)fmaxf(acc[ci][m][1] + bv.y, 0.f);
                o[2] = (f16)fmaxf(acc[ci][m][2] + bv.z, 0.f);
                o[3] = (f16)fmaxf(acc[ci][m][3] + bv.w, 0.f);
                *(f16x4*)(vout + (size_t)sposv[m] * 128 + f0) = o;
            }
        }
    }
    if constexpr (EPI == 1) {
#pragma unroll
        for (int m = 0; m < 4; ++m) {
            float r = preg[m];
            r += __shfl_xor(r, 16);
            r += __shfl_xor(r, 32);
            if (quad == 0) lpart[wave * 64 + m * 16 + l15] = r;
        }
    }
}

// ---- simple layer variant (node_kernel) ----
template<int K, int N>
__device__ __forceinline__ void mfma_layer_basic(const f16* in, int inoff,
        const f16* __restrict__ wt, const float* __restrict__ bias,
        f16* out, int outoff, int tid)
{
    const int wave = tid >> 6;
    const int lane = tid & 63;
    const int l15  = lane & 15;
    const int quad = lane >> 4;
    constexpr int NCT = N >> 4;
    constexpr int NKS = K >> 5;
    f16x8 af[4][NKS];
#pragma unroll
    for (int ms = 0; ms < 4; ++ms)
#pragma unroll
        for (int ks = 0; ks < NKS; ++ks)
            af[ms][ks] = *(const f16x8*)(in + swz(ms * 16 + l15, inoff + ks * 32 + quad * 8));
#pragma unroll 1
    for (int ct = wave; ct < NCT; ct += 4) {
        f16x8 bf[NKS];
        const f16* wrow = wt + (size_t)(ct * 16 + l15) * K + quad * 8;
#pragma unroll
        for (int ks = 0; ks < NKS; ++ks) bf[ks] = *(const f16x8*)(wrow + ks * 32);
        const int f0 = ct * 16 + quad * 4;
        const float4 bv = *(const float4*)(bias + f0);
#pragma unroll
        for (int ms = 0; ms < 4; ++ms) {
            f32x4 acc = {0.f, 0.f, 0.f, 0.f};
#pragma unroll
            for (int ks = 0; ks < NKS; ++ks)
                acc = __builtin_amdgcn_mfma_f32_16x16x32_f16(bf[ks], af[ms][ks], acc, 0, 0, 0);
            f16x4 o;
            o[0] = (f16)fmaxf(acc[0] + bv.x, 0.f);
            o[1] = (f16)fmaxf(acc[1] + bv.y, 0.f);
            o[2] = (f16)fmaxf(acc[2] + bv.z, 0.f);
            o[3] = (f16)fmaxf(acc[3] + bv.w, 0.f);
            *(f16x4*)(out + swz(ms * 16 + l15, outoff + f0)) = o;
        }
    }
}

// ---- prep: transpose-convert weights to f16 [N][Kpad] ----
struct WSeg { const float* src; int K, N, Kpad, dstOff; };
struct WSegs { WSeg s[9]; };

__global__ void prep_kernel(WSegs segs, f16* __restrict__ wt) {
    int idx = blockIdx.x * 256 + threadIdx.x;
    if (idx >= WT_TOTAL) return;
    int off = idx;
#pragma unroll
    for (int i = 0; i < 9; ++i) {
        int sz = segs.s[i].N * segs.s[i].Kpad;
        if (off < sz) {
            int n = off / segs.s[i].Kpad;
            int k = off - n * segs.s[i].Kpad;
            f16 val = (f16)0.f;
            if (k < segs.s[i].K) val = (f16)segs.s[i].src[k * segs.s[i].N + n];
            wt[segs.s[i].dstOff + off] = val;
            return;
        }
        off -= sz;
    }
}

// ---- sort step 1: histogram of receivers ----
__global__ void hist_kernel(const int* __restrict__ receivers, int* __restrict__ cnt) {
    int e = blockIdx.x * 256 + threadIdx.x;
    atomicAdd(&cnt[receivers[e]], 1);
}

// ---- sort step 2: exclusive scan ----
__global__ __launch_bounds__(1024) void scan_kernel(int* __restrict__ cnt, int* __restrict__ base) {
    __shared__ int psum[1024];
    const int tid = threadIdx.x;
    const int CH = (NN_NODE + 1023) / 1024;
    const int lo = tid * CH;
    const int hi = min(lo + CH, NN_NODE);
    int s = 0;
    for (int i = lo; i < hi; ++i) s += cnt[i];
    psum[tid] = s;
    __syncthreads();
    for (int d = 1; d < 1024; d <<= 1) {
        int v = (tid >= d) ? psum[tid - d] : 0;
        __syncthreads();
        psum[tid] += v;
        __syncthreads();
    }
    int run = psum[tid] - s;
    for (int i = lo; i < hi; ++i) {
        int c = cnt[i];
        base[i] = run;
        cnt[i] = run;
        run += c;
    }
}

// ---- K1: per-edge encoder + attention logit + value; 64 edges/block ----
// Single 32KB in-place buffer; register-lean mlayerR -> 4 blocks/CU,
// 16 waves/CU (launch_bounds(256,4) caps VGPR at 128).
// Column map: z 0-31; a1/a2 0-255; q 0-127; h0 128-255; v1 0-255.
__global__ __launch_bounds__(256, 4) void edge_kernel(
        const float* __restrict__ nodes, const float* __restrict__ edges,
        const int* __restrict__ senders, const int* __restrict__ receivers,
        const f16* __restrict__ wt,
        const float* __restrict__ mb0, const float* __restrict__ mb1, const float* __restrict__ mb2,
        const float* __restrict__ ab0, const float* __restrict__ ab1,
        const float* __restrict__ aw2, const float* __restrict__ ab2,
        const float* __restrict__ vb0, const float* __restrict__ vb1,
        f16* __restrict__ vout, float* __restrict__ wlog, int* __restrict__ cursor)
{
    __shared__ f16 buf[64 * 256];   // 32 KB
    __shared__ int spos[64];
    __shared__ float lpart[256];
    const int tid = threadIdx.x;
    const int e0 = blockIdx.x * 64;

    // stage z: one b128 write per thread. Thread (e, c) owns chunk c of row e.
    // chunk0 = [s.xyz, r.xyz, edge01], chunk1 = [edge23, 0...], chunk2/3 = 0.
    {
        const int e = tid & 63, c = tid >> 6;
        f16x8 zv = {(f16)0.f,(f16)0.f,(f16)0.f,(f16)0.f,(f16)0.f,(f16)0.f,(f16)0.f,(f16)0.f};
        if (c == 0) {
            int s = senders[e0 + e];
            int r = receivers[e0 + e];
            const float2 ev = *(const float2*)(edges + (size_t)(e0 + e) * 4);
            zv[0] = (f16)nodes[s * 3 + 0]; zv[1] = (f16)nodes[s * 3 + 1]; zv[2] = (f16)nodes[s * 3 + 2];
            zv[3] = (f16)nodes[r * 3 + 0]; zv[4] = (f16)nodes[r * 3 + 1]; zv[5] = (f16)nodes[r * 3 + 2];
            zv[6] = (f16)ev.x; zv[7] = (f16)ev.y;
        } else if (c == 1) {
            const float2 ev = *(const float2*)(edges + (size_t)(e0 + e) * 4 + 2);
            zv[0] = (f16)ev.x; zv[1] = (f16)ev.y;
        }
        *(f16x8*)(buf + e * 256 + ((c ^ (e & 7)) << 3)) = zv;
    }
    __syncthreads();

    // L1: z(0-31) -> a1(0-255), overlapping -> IBAR
    mlayerR< 32, 256, 0, 1>(buf, 0, 0, wt + WT_MW0, mb0, nullptr, nullptr, nullptr, nullptr, tid);
    __syncthreads();
    // MW1: a1 -> a2 (0-255), in-place -> IBAR
    mlayerR<256, 256, 0, 1>(buf, 0, 0, wt + WT_MW1, mb1, nullptr, nullptr, nullptr, nullptr, tid);
    __syncthreads();
    // MW2: a2 -> q (0-127), in-place -> IBAR
    mlayerR<256, 128, 0, 1>(buf, 0, 0, wt + WT_MW2, mb2, nullptr, nullptr, nullptr, nullptr, tid);
    __syncthreads();
    // AW0: q(0-127) -> h0(128-255), disjoint -> no IBAR
    mlayerR<128, 128, 0, 0>(buf, 0, 128, wt + WT_AW0, ab0, nullptr, nullptr, nullptr, nullptr, tid);
    __syncthreads();
    // AW1: h0 -> logit partials (lpart only, no LDS buf writes) -> no IBAR
    mlayerR<128, 128, 1, 0>(buf, 128, 0, wt + WT_AW1, ab1, aw2, lpart, nullptr, nullptr, tid);
    __syncthreads();

    // finalize logits (wave 0) while other waves start VW0 (reads q only)
    if (tid < 64) {
        float wv = lpart[tid] + lpart[64 + tid] + lpart[128 + tid] + lpart[192 + tid] + ab2[0];
        int r = receivers[e0 + tid];
        int pos = atomicAdd(&cursor[r], 1);
        spos[tid] = pos;
        wlog[pos] = wv;
    }
    // VW0: q(0-127) -> v1(0-255), overlapping -> IBAR
    mlayerR<128, 256, 0, 1>(buf, 0, 0, wt + WT_VW0, vb0, nullptr, nullptr, nullptr, nullptr, tid);
    __syncthreads();   // also makes spos visible before VW1 reads it
    // VW1: v1 -> v (global, receiver-sorted slots), no LDS writes
    mlayerR<256, 128, 2, 0>(buf, 0, 0, wt + WT_VW1, vb1, nullptr, nullptr, vout, spos, tid);
}

// ---- K2: per-node segmented softmax + weighted aggregation (1 wave / node) ----
__global__ __launch_bounds__(256) void aggregate_kernel(
        const float* __restrict__ wlog, const f16* __restrict__ v,
        const int* __restrict__ base, float* __restrict__ aggr)
{
    const int tid = threadIdx.x;
    const int n = blockIdx.x * 4 + (tid >> 6);
    const int lane = tid & 63;
    const int st = base[n];
    const int en = (n == NN_NODE - 1) ? NN_EDGE : base[n + 1];

    float mx = -1e9f;
    for (int i = st + lane; i < en; i += 64) mx = fmaxf(mx, wlog[i]);
#pragma unroll
    for (int d = 1; d < 64; d <<= 1) mx = fmaxf(mx, __shfl_xor(mx, d));

    float sm = 0.f;
    for (int i = st + lane; i < en; i += 64) sm += __expf(wlog[i] - mx);
#pragma unroll
    for (int d = 1; d < 64; d <<= 1) sm += __shfl_xor(sm, d);
    const float inv = 1.f / (sm + 1e-12f);

    float acc0 = 0.f, acc1 = 0.f;
    const f16* vp = v + (size_t)st * 128 + lane * 2;
    for (int i = st; i < en; ++i, vp += 128) {
        float attn = __expf(wlog[i] - mx) * inv;
        f16x2 vv = *(const f16x2*)vp;
        acc0 += attn * (float)vv[0];
        acc1 += attn * (float)vv[1];
    }
    float2 o; o.x = acc0; o.y = acc1;
    *(float2*)(aggr + (size_t)n * 128 + lane * 2) = o;
}

// ---- K3: node decoder (64-node tiles) ----
__global__ __launch_bounds__(256, 2) void node_kernel(
        const float* __restrict__ aggr, const f16* __restrict__ wt,
        const float* __restrict__ ub0, const float* __restrict__ ub1,
        const float* __restrict__ uw2, const float* __restrict__ ub2,
        float* __restrict__ out)
{
    __shared__ f16 ldsbuf[2 * 64 * 256];
    f16* bufA = ldsbuf;
    f16* bufB = ldsbuf + 64 * 256;
    const int tid = threadIdx.x;
    const int n0 = blockIdx.x * 64;
    {
        int row = tid >> 2, j = tid & 3;
        int n = n0 + row;
        if (n < NN_NODE) {
            const float4* src = (const float4*)(aggr + (size_t)n * 128 + j * 32);
#pragma unroll
            for (int i = 0; i < 8; ++i) {
                float4 t4 = src[i];
                int c = j * 32 + i * 4;
                bufA[swz(row, c + 0)] = (f16)t4.x;
                bufA[swz(row, c + 1)] = (f16)t4.y;
                bufA[swz(row, c + 2)] = (f16)t4.z;
                bufA[swz(row, c + 3)] = (f16)t4.w;
            }
        } else {
#pragma unroll
            for (int i = 0; i < 32; ++i) bufA[swz(row, j * 32 + i)] = (f16)0.f;
        }
    }
    __syncthreads();
    mfma_layer_basic<128, 256>(bufA, 0, wt + WT_UW0, ub0, bufB, 0, tid); __syncthreads();
    mfma_layer_basic<256, 256>(bufB, 0, wt + WT_UW1, ub1, bufA, 0, tid); __syncthreads();
    {
        int e = tid >> 2, part = tid & 3;
        float sum = 0.f;
        for (int c = part * 64; c < part * 64 + 64; ++c)
            sum += (float)bufA[swz(e, c)] * uw2[c];
        sum += __shfl_down(sum, 2);
        sum += __shfl_down(sum, 1);
        int n = n0 + e;
        if (part == 0 && n < NN_NODE) out[n] = sum + ub2[0];
    }
}

extern "C" void kernel_launch(void* const* d_in, const int* in_sizes, int n_in,
                              void* d_out, int out_size, void* d_ws, size_t ws_size,
                              hipStream_t stream)
{
    const float* nodes     = (const float*)d_in[0];
    const float* edges     = (const float*)d_in[1];
    const int*   senders   = (const int*)d_in[2];
    const int*   receivers = (const int*)d_in[3];
    const float* mw0 = (const float*)d_in[4];  const float* mb0 = (const float*)d_in[5];
    const float* mw1 = (const float*)d_in[6];  const float* mb1 = (const float*)d_in[7];
    const float* mw2 = (const float*)d_in[8];  const float* mb2 = (const float*)d_in[9];
    const float* aw0 = (const float*)d_in[10]; const float* ab0 = (const float*)d_in[11];
    const float* aw1 = (const float*)d_in[12]; const float* ab1 = (const float*)d_in[13];
    const float* aw2 = (const float*)d_in[14]; const float* ab2 = (const float*)d_in[15];
    const float* vw0 = (const float*)d_in[16]; const float* vb0 = (const float*)d_in[17];
    const float* vw1 = (const float*)d_in[18]; const float* vb1 = (const float*)d_in[19];
    const float* uw0 = (const float*)d_in[20]; const float* ub0 = (const float*)d_in[21];
    const float* uw1 = (const float*)d_in[22]; const float* ub1 = (const float*)d_in[23];
    const float* uw2 = (const float*)d_in[24]; const float* ub2 = (const float*)d_in[25];

    char* ws = (char*)d_ws;
    f16*   wt   = (f16*)ws;
    f16*   vbuf = (f16*)(ws + V_OFF);
    float* wlog = (float*)(ws + WL_OFF);
    int*   cnt  = (int*)(ws + CNT_OFF);
    int*   base = (int*)(ws + BASE_OFF);
    float* aggr = (float*)(ws + AGGR_OFF);
    float* out  = (float*)d_out;

    hipMemsetAsync(cnt, 0, NN_NODE * sizeof(int), stream);

    WSegs segs = {{
        { mw0,  10, 256,  32, WT_MW0 },
        { mw1, 256, 256, 256, WT_MW1 },
        { mw2, 256, 128, 256, WT_MW2 },
        { aw0, 128, 128, 128, WT_AW0 },
        { aw1, 128, 128, 128, WT_AW1 },
        { vw0, 128, 256, 128, WT_VW0 },
        { vw1, 256, 128, 256, WT_VW1 },
        { uw0, 128, 256, 128, WT_UW0 },
        { uw1, 256, 256, 256, WT_UW1 },
    }};
    prep_kernel<<<(WT_TOTAL + 255) / 256, 256, 0, stream>>>(segs, wt);

    hist_kernel<<<NN_EDGE / 256, 256, 0, stream>>>(receivers, cnt);
    scan_kernel<<<1, 1024, 0, stream>>>(cnt, base);

    edge_kernel<<<NN_EDGE / 64, 256, 0, stream>>>(nodes, edges, senders, receivers, wt,
        mb0, mb1, mb2, ab0, ab1, aw2, ab2, vb0, vb1, vbuf, wlog, cnt);

    aggregate_kernel<<<NN_NODE / 4, 256, 0, stream>>>(wlog, vbuf, base, aggr);

    node_kernel<<<(NN_NODE + 63) / 64, 256, 0, stream>>>(aggr, wt, ub0, ub1, uw2, ub2, out);
}